// Round 15
// baseline (55.688 us; speedup 1.0000x reference)
//
#include <hip/hip_runtime.h>
#include <hip/hip_bf16.h>

#define SEQ   512
#define LPAD  64
#define RPAD  68
#define TOT   (SEQ + LPAD + RPAD)   // 644 float4 per sequence
#define C1f   14.426950408889634f    // 1/(gamma*ln2), gamma=0.1
#define K1f   0.069314718055994531f  // gamma*ln2

#if __has_builtin(__builtin_amdgcn_exp2f)
#define EXP2(x) __builtin_amdgcn_exp2f(x)
#else
#define EXP2(x) exp2f(x)
#endif

#define SB() __builtin_amdgcn_sched_barrier(0)

__device__ __forceinline__ float cost4(float4 X, float4 Y) {
  return fabsf(X.x - Y.x) + fabsf(X.y - Y.y) + fabsf(X.z - Y.z) + fabsf(X.w - Y.w);
}

// f64 lane shifts via DPP wave shifts: VALU, 0-fill at edges (0 == exp-domain BIG).
__device__ __forceinline__ double dshr1(double x) {  // lane t <- lane t+1; lane63 <- 0
  int lo = __builtin_amdgcn_update_dpp(0, __double2loint(x), 0x138, 0xF, 0xF, true);
  int hi = __builtin_amdgcn_update_dpp(0, __double2hiint(x), 0x138, 0xF, 0xF, true);
  return __hiloint2double(hi, lo);
}
__device__ __forceinline__ double dshl1(double x) {  // lane t <- lane t-1; lane0 <- 0
  int lo = __builtin_amdgcn_update_dpp(0, __double2loint(x), 0x130, 0xF, 0xF, true);
  int hi = __builtin_amdgcn_update_dpp(0, __double2hiint(x), 0x130, 0xF, 0xF, true);
  return __hiloint2double(hi, lo);
}
__device__ __forceinline__ double pow2i(int k) {     // 2^k exactly, |k| <= ~500
  union { unsigned long long u; double d; } v;
  v.u = ((unsigned long long)(1023 + k)) << 52;
  return v.d;
}

// ---- 1 cell/lane, band u = t in [0,63]; f64 exp-domain DP (R11/R14 algebra) ----
// pair n covers diags p=2n+1 (odd) and p=2n+2 (even).
//   odd  cell: i = n+t-31, j = n-t+32; neighbors: diag=dA, left=dB, up=dshl1(dB)
//   even cell: i = n+t-30, j = n-t+32; neighbors: diag=dB, up=nA, left=dshr1(nA)
// windows: X0 = x[n+t-31], X1 = x[n+t-30], Y0 = y[n-t+32]
// 12 rotating slots; pair m -> slot m%12. FOUR pairs per SB scheduling region:
// region r: LOADW pairs 4r+8..4r+11, COMPP pairs 4r+4..4r+7, CHAIN pairs 4r..4r+3.
#define DECLS(s) \
  float4 X0##s, X1##s, Y0##s; \
  double Po##s, Pe##s; \
  int k1##s, k2##s;

#define LOADW(s, m) do { \
    X0##s = pX[(m)]; X1##s = pX[(m) + 1]; Y0##s = pY[(m)]; } while (0)

// P factors for the pair in slot s with scale bump folded into the exp2 arg.
#define COMPP(s, bump) do { \
    k1##s = (bump) >> 1; k2##s = (bump) - k1##s; \
    float _f1 = (float)k1##s, _f2 = (float)k2##s; \
    Po##s = (double)EXP2(fmaf(cost4(X0##s, Y0##s), -C1f, _f1)); \
    Pe##s = (double)EXP2(fmaf(cost4(X1##s, Y0##s), -C1f, _f2)); } while (0)

// f64 recurrence for one pair; sp = previous pair's slot (supplies k2prev).
#define CHAIN(s, sp) do { \
    double _s2p = pow2i(k2##sp), _s1c = pow2i(k1##s); \
    double _up = dshl1(dB); \
    double _nA = Po##s * fma(dA, _s2p, dB + _up); \
    double _lf = dshr1(_nA); \
    double _nB = Pe##s * fma(dB, _s1c, _nA + _lf); \
    dA = _nA; dB = _nB; } while (0)

// lag-queue residual renorm feedback, once per region (4 pairs).
// center cell = lane31 even diag, always valid. Clamp +-600 (drift ~65 bits/pair).
#define FEEDBACK() do { \
    int _hib = __builtin_amdgcn_readlane(__double2hiint(dB), 31); \
    int _def = 1023 - ((_hib >> 20) & 0x7ff); \
    Ktot += bq0; \
    int _nb = _def - bq1; _nb = _nb < -600 ? -600 : (_nb > 600 ? 600 : _nb); \
    bq0 = bq1; bq1 = _nb; } while (0)

// Region: chains A..D (pairs 4r..4r+3), COMPPs E..H (4r+4..4r+7, region bump
// split 4 ways so each exp2f arg stays < ~90), loads I..L (4r+8..4r+11).
// L == (A-1) mod 12 also holds pair 4r-1's k2 (windows overwritten, k's kept).
#define GROUP4(A,B,C,D, E,F,G,H, I,J,K,L, m) do { \
    SB(); \
    LOADW(I, (m)); LOADW(J, (m) + 1); LOADW(K, (m) + 2); LOADW(L, (m) + 3); \
    { int _b = bq1, _q = _b >> 2, _r = _b - 3 * _q; \
      COMPP(E, _q); COMPP(F, _q); COMPP(G, _q); COMPP(H, _r); } \
    CHAIN(A, L); CHAIN(B, A); CHAIN(C, B); CHAIN(D, C); \
    FEEDBACK(); } while (0)

// Blocks 0..95: banded soft-DTW -> atomic contributions to out[0],out[1].
// Block 96: KL + transition losses -> atomic out[0],out[2..4]. One kernel total.
__global__ __launch_bounds__(256, 1) void sdtw_fused_kernel(
    const float* __restrict__ at,    // [32,512,4]
    const float* __restrict__ mu,    // [32,64]
    const float* __restrict__ lv,    // [32,64]
    const float* __restrict__ ptc,   // [32,1]
    const float* __restrict__ gt,    // [32,512,4]
    float* __restrict__ out)         // [5], pre-zeroed by memsetAsync
{
  __shared__ float4 sx[TOT];
  __shared__ float4 sy[TOT];
  __shared__ float s_g[32], s_ps[32], s_kl[32];

  const int blk = blockIdx.x;
  const int t   = threadIdx.x;

  if (blk < 96) {
    const float* xs;
    const float* ys;
    if (blk < 32)      { xs = at + (size_t)blk        * SEQ * 4; ys = gt + (size_t)blk * SEQ * 4; }
    else if (blk < 64) { xs = at + (size_t)(blk - 32) * SEQ * 4; ys = xs; }
    else               { xs = gt + (size_t)(blk - 64) * SEQ * 4; ys = xs; }

    for (int i = t; i < LPAD; i += 256) {
      sx[i] = make_float4(0.f, 0.f, 0.f, 0.f);
      sy[i] = make_float4(0.f, 0.f, 0.f, 0.f);
    }
    for (int i = LPAD + SEQ + t; i < TOT; i += 256) {
      sx[i] = make_float4(0.f, 0.f, 0.f, 0.f);
      sy[i] = make_float4(0.f, 0.f, 0.f, 0.f);
    }
    for (int i = t; i < SEQ; i += 256) {
      sx[LPAD + i] = ((const float4*)xs)[i];
      sy[LPAD + i] = ((const float4*)ys)[i];
    }
    __syncthreads();
    if (t >= 64) return;   // single wave runs the wavefront; no more barriers

    const float4* sxp = sx + LPAD;
    const float4* syp = sy + LPAD;
    const float4* pX = sxp + (t - 31);   // pX[m] = x[m+t-31]
    const float4* pY = syp + (32 - t);   // pY[m] = y[m-t+32]

    // seed: diag 0 = (0,0) at lane31 (even diag of pair -1; slot 11, k2_11 = 0)
    float a0 = -C1f * cost4(sxp[0], syp[0]);
    int   n0 = (int)floorf(a0);
    double e00 = (double)EXP2(a0 - (float)n0);
    double dA = 0.0;
    double dB = (t == 31) ? e00 : 0.0;
    int Ktot = -n0;
    int bq0 = 0, bq1 = 0;

    DECLS(0) DECLS(1) DECLS(2) DECLS(3) DECLS(4)  DECLS(5)
    DECLS(6) DECLS(7) DECLS(8) DECLS(9) DECLS(10) DECLS(11)
    k211 = 0; k111 = 0;   // pair -1's bumps (read by CHAIN(0,11) in region 0)

    // prologue: windows for pairs 0..7; P for pairs 0..3 (bumps 0)
    LOADW(0, 0); LOADW(1, 1); LOADW(2, 2); LOADW(3, 3);
    LOADW(4, 4); LOADW(5, 5); LOADW(6, 6); LOADW(7, 7);
    COMPP(0, 0); COMPP(1, 0); COMPP(2, 0); COMPP(3, 0);

    // steady: 126 regions (chain pairs 0..503), 3 regions per iteration
    #pragma unroll 1
    for (int g = 0; g < 42; ++g) {
      const int m = 12 * g;
      GROUP4(0,1,2,3,   4,5,6,7,   8,9,10,11, m + 8);
      GROUP4(4,5,6,7,   8,9,10,11, 0,1,2,3,   m + 12);
      GROUP4(8,9,10,11, 0,1,2,3,   4,5,6,7,   m + 16);
    }
    // tail 1: COMPP pairs 508..510 (slots 4,5,6; split bump 3 ways), chain 504..507
    SB();
    { int _b = bq1, _q = _b / 3, _r = _b - 2 * _q;
      COMPP(4, _q); COMPP(5, _q); COMPP(6, _r); }
    CHAIN(0, 11); CHAIN(1, 0); CHAIN(2, 1); CHAIN(3, 2);
    FEEDBACK();
    // tail 2: chain pairs 508..510
    SB();
    CHAIN(4, 3); CHAIN(5, 4); CHAIN(6, 5);
    Ktot += bq0;   // bump consumed by tail-1's COMPP

    if (t == 31) {
      // final cell (511,511) = even diag of pair 510, lane31
      // v = -gamma*ln(E_true) = -K1f*(log2(stored) - Ktot)
      unsigned long long bits = __double_as_longlong(dB);
      int ee = (int)((bits >> 52) & 0x7ffull);
      double mant = __longlong_as_double((bits & 0xFFFFFFFFFFFFFull) | (1023ull << 52));
      double l2 = (double)(ee - 1023) + (double)__log2f((float)mant);
      float v = (float)(-(double)K1f * (l2 - (double)Ktot));
      // recon = (sum_{b<32} v_b - 0.5*(v_xx + v_yy)) / 1024
      float c = ((blk < 32) ? (1.0f / 1024.0f) : (-0.5f / 1024.0f)) * v;
      atomicAdd(out + 0, c);
      atomicAdd(out + 1, c);
    }
    return;
  }

  // ---------- loss block (blk == 96), 256 threads: 8 per batch element ----------
  const int b = t >> 3, seg = t & 7;

  float s = 0.f;
  {
    const float* mb = mu + b * 64 + seg * 8;
    const float* lb = lv + b * 64 + seg * 8;
    #pragma unroll
    for (int z = 0; z < 8; ++z) {
      float m = mb[z], l = lb[z];
      s += 1.0f + l - m * m - __expf(l);
    }
  }
  s += __shfl_down(s, 4, 8);
  s += __shfl_down(s, 2, 8);
  s += __shfl_down(s, 1, 8);

  float g = 0.f, ps = 0.f;
  {
    const int n0 = seg * 64;
    const int nstart = (seg == 0) ? 1 : n0;
    const float* gb = gt + (size_t)b * SEQ * 4 + 2;
    const float* ab = at + (size_t)b * SEQ * 4 + 2;
    float pg = gb[(nstart - 1) * 4];
    float pp = 1.0f / (1.0f + __expf((0.5f - ab[(nstart - 1) * 4]) * 10.0f));
    for (int n = nstart; n < n0 + 64; ++n) {
      float cg = gb[n * 4]; g += fabsf(cg - pg); pg = cg;
      float cp = 1.0f / (1.0f + __expf((0.5f - ab[n * 4]) * 10.0f));
      ps += fabsf(cp - pp); pp = cp;
    }
  }
  g  += __shfl_down(g, 4, 8);  g  += __shfl_down(g, 2, 8);  g  += __shfl_down(g, 1, 8);
  ps += __shfl_down(ps, 4, 8); ps += __shfl_down(ps, 2, 8); ps += __shfl_down(ps, 1, 8);

  if (seg == 0) {
    s_g[b]  = g;
    s_ps[b] = ps;
    s_kl[b] = fmaxf(-0.5f * s - 0.5f, 0.0f);
  }
  __syncthreads();

  if (t < 32) {
    float gv  = s_g[t];
    float kl  = s_kl[t];
    float d   = ptc[t] - gv;  float aux = d * d;
    float e   = s_ps[t] - gv; float tr  = e * e;
    kl  += __shfl_down(kl, 16, 32); aux += __shfl_down(aux, 16, 32); tr += __shfl_down(tr, 16, 32);
    kl  += __shfl_down(kl,  8, 32); aux += __shfl_down(aux,  8, 32); tr += __shfl_down(tr,  8, 32);
    kl  += __shfl_down(kl,  4, 32); aux += __shfl_down(aux,  4, 32); tr += __shfl_down(tr,  4, 32);
    kl  += __shfl_down(kl,  2, 32); aux += __shfl_down(aux,  2, 32); tr += __shfl_down(tr,  2, 32);
    kl  += __shfl_down(kl,  1, 32); aux += __shfl_down(aux,  1, 32); tr += __shfl_down(tr,  1, 32);
    if (t == 0) {
      float klm  = kl  * (1.0f / 32.0f);
      float auxm = aux * (1.0f / 32.0f);
      float trm  = tr  * (1.0f / 32.0f);
      atomicAdd(out + 0, klm + 0.1f * auxm + 0.5f * trm);
      atomicAdd(out + 2, klm);
      atomicAdd(out + 3, auxm);
      atomicAdd(out + 4, trm);
    }
  }
}

extern "C" void kernel_launch(void* const* d_in, const int* in_sizes, int n_in,
                              void* d_out, int out_size, void* d_ws, size_t ws_size,
                              hipStream_t stream) {
  const float* at  = (const float*)d_in[0];
  const float* mu  = (const float*)d_in[1];
  const float* lv  = (const float*)d_in[2];
  const float* ptc = (const float*)d_in[3];
  const float* gt  = (const float*)d_in[4];
  float* out = (float*)d_out;

  hipMemsetAsync(d_out, 0, 5 * sizeof(float), stream);
  sdtw_fused_kernel<<<97, 256, 0, stream>>>(at, mu, lv, ptc, gt, out);
}

// Round 16
// 52.332 us; speedup vs baseline: 1.0641x; 1.0641x over previous
//
#include <hip/hip_runtime.h>
#include <hip/hip_bf16.h>

#define SEQ   512
#define LPAD  64
#define RPAD  68
#define TOT   (SEQ + LPAD + RPAD)   // 644 float4 per sequence
#define C1f   14.426950408889634f    // 1/(gamma*ln2), gamma=0.1
#define K1f   0.069314718055994531f  // gamma*ln2

#if __has_builtin(__builtin_amdgcn_exp2f)
#define EXP2(x) __builtin_amdgcn_exp2f(x)
#else
#define EXP2(x) exp2f(x)
#endif

#define SB() __builtin_amdgcn_sched_barrier(0)

__device__ __forceinline__ float cost4(float4 X, float4 Y) {
  return fabsf(X.x - Y.x) + fabsf(X.y - Y.y) + fabsf(X.z - Y.z) + fabsf(X.w - Y.w);
}

// f64 lane shifts via DPP wave shifts: VALU, 0-fill at edges (0 == exp-domain BIG).
__device__ __forceinline__ double dshr1(double x) {  // lane t <- lane t+1; lane63 <- 0
  int lo = __builtin_amdgcn_update_dpp(0, __double2loint(x), 0x138, 0xF, 0xF, true);
  int hi = __builtin_amdgcn_update_dpp(0, __double2hiint(x), 0x138, 0xF, 0xF, true);
  return __hiloint2double(hi, lo);
}
__device__ __forceinline__ double dshl1(double x) {  // lane t <- lane t-1; lane0 <- 0
  int lo = __builtin_amdgcn_update_dpp(0, __double2loint(x), 0x130, 0xF, 0xF, true);
  int hi = __builtin_amdgcn_update_dpp(0, __double2hiint(x), 0x130, 0xF, 0xF, true);
  return __hiloint2double(hi, lo);
}
__device__ __forceinline__ double pow2i(int k) {     // 2^k exactly, |k| <= ~500
  union { unsigned long long u; double d; } v;
  v.u = ((unsigned long long)(1023 + k)) << 52;
  return v.d;
}

// ---- 1 cell/lane, band u = t in [0,63]; f64 exp-domain DP (R14 algebra) ----
// pair n covers diags p=2n+1 (odd) and p=2n+2 (even).
//   odd  cell: i = n+t-31, j = n-t+32; neighbors: diag=dA, left=dB, up=dshl1(dB)
//   even cell: i = n+t-30, j = n-t+32; neighbors: diag=dB, up=nA, left=dshr1(nA)
// windows: X0 = x[n+t-31], Y0 = y[n-t+32]; X1 (= x[n+1+t-31]) is the NEXT
// slot's X0 (pair m+1), so only 2 ds_reads per pair.
// 8 rotating slots; pair m -> slot m%8. TWO pairs per SB scheduling region.
// Region r: LOADW pairs 2r+6,2r+7; COMPP pairs 2r+2,2r+3; CHAIN pairs 2r,2r+1.
#define DECLS(s) \
  float4 X0##s, Y0##s; \
  double Po##s, Pe##s; \
  int k1##s, k2##s;

#define LOADW(s, m) do { \
    X0##s = pX[(m)]; Y0##s = pY[(m)]; } while (0)

// P factors for pair in slot s; sn = next pair's slot (supplies X1 = X0[m+1]).
#define COMPP(s, sn, bump) do { \
    k1##s = (bump) >> 1; k2##s = (bump) - k1##s; \
    float _f1 = (float)k1##s, _f2 = (float)k2##s; \
    Po##s = (double)EXP2(fmaf(cost4(X0##s, Y0##s), -C1f, _f1)); \
    Pe##s = (double)EXP2(fmaf(cost4(X0##sn, Y0##s), -C1f, _f2)); } while (0)

// f64 recurrence for one pair; sp = previous pair's slot (supplies k2prev).
#define CHAIN(s, sp) do { \
    double _s2p = pow2i(k2##sp), _s1c = pow2i(k1##s); \
    double _up = dshl1(dB); \
    double _nA = Po##s * fma(dA, _s2p, dB + _up); \
    double _lf = dshr1(_nA); \
    double _nB = Pe##s * fma(dB, _s1c, _nA + _lf); \
    dA = _nA; dB = _nB; } while (0)

// lag-queue residual renorm feedback, once per region (2 pairs).
// center cell = lane31 even diag (n+1,n+1), always valid.
#define FEEDBACK() do { \
    int _hib = __builtin_amdgcn_readlane(__double2hiint(dB), 31); \
    int _def = 1023 - ((_hib >> 20) & 0x7ff); \
    Ktot += bq0; \
    int _nb = _def - bq1; _nb = _nb < -250 ? -250 : (_nb > 250 ? 250 : _nb); \
    bq0 = bq1; bq1 = _nb; } while (0)

// Region r: A=slot(2r)%8, B=A+1, C=A+2, D=A+3, E=A+4 (X1 source for COMPP(D)),
// L0=A+6, L1=A+7 (mod 8). L1 also = slot(2r-1): its k2 is pair 2r-1's
// (COMPP'd two regions ago); LOADW(L1) below only overwrites windows, not k's.
#define GROUP2(A, B, C, D, E, L0, L1, m) do { \
    SB(); \
    LOADW(L0, (m));    LOADW(L1, (m) + 1); \
    COMPP(C, D, bq1);  COMPP(D, E, 0); \
    CHAIN(A, L1);      CHAIN(B, A); \
    FEEDBACK(); } while (0)

// Blocks 0..95: banded soft-DTW per extended batch element -> ws[b].
// Block 96: KL + transition-count losses -> ws[96..98]. Runs concurrently.
__global__ __launch_bounds__(256, 1) void sdtw_fused_kernel(
    const float* __restrict__ at,    // [32,512,4]
    const float* __restrict__ mu,    // [32,64]
    const float* __restrict__ lv,    // [32,64]
    const float* __restrict__ ptc,   // [32,1]
    const float* __restrict__ gt,    // [32,512,4]
    float* __restrict__ ws)          // [0..95]=v, [96]=klS, [97]=auxS, [98]=trS
{
  __shared__ float4 sx[TOT];
  __shared__ float4 sy[TOT];
  __shared__ float s_g[32], s_ps[32], s_kl[32];

  const int blk = blockIdx.x;
  const int t   = threadIdx.x;

  if (blk < 96) {
    const float* xs;
    const float* ys;
    if (blk < 32)      { xs = at + (size_t)blk        * SEQ * 4; ys = gt + (size_t)blk * SEQ * 4; }
    else if (blk < 64) { xs = at + (size_t)(blk - 32) * SEQ * 4; ys = xs; }
    else               { xs = gt + (size_t)(blk - 64) * SEQ * 4; ys = xs; }

    for (int i = t; i < LPAD; i += 256) {
      sx[i] = make_float4(0.f, 0.f, 0.f, 0.f);
      sy[i] = make_float4(0.f, 0.f, 0.f, 0.f);
    }
    for (int i = LPAD + SEQ + t; i < TOT; i += 256) {
      sx[i] = make_float4(0.f, 0.f, 0.f, 0.f);
      sy[i] = make_float4(0.f, 0.f, 0.f, 0.f);
    }
    for (int i = t; i < SEQ; i += 256) {
      sx[LPAD + i] = ((const float4*)xs)[i];
      sy[LPAD + i] = ((const float4*)ys)[i];
    }
    __syncthreads();
    if (t >= 64) return;   // single wave runs the wavefront; no more barriers

    const float4* sxp = sx + LPAD;
    const float4* syp = sy + LPAD;
    const float4* pX = sxp + (t - 31);   // pX[m] = x[m+t-31]
    const float4* pY = syp + (32 - t);   // pY[m] = y[m-t+32]

    // seed: diag 0 = (0,0) at lane31 (even diag of pair -1; slot 7, k2_7 = 0)
    float a0 = -C1f * cost4(sxp[0], syp[0]);
    int   n0 = (int)floorf(a0);
    double e00 = (double)EXP2(a0 - (float)n0);
    double dA = 0.0;
    double dB = (t == 31) ? e00 : 0.0;
    int Ktot = -n0;
    int bq0 = 0, bq1 = 0;

    DECLS(0) DECLS(1) DECLS(2) DECLS(3)
    DECLS(4) DECLS(5) DECLS(6) DECLS(7)
    k27 = 0; k17 = 0;   // pair -1's bumps (read by CHAIN(0,7) in region 0)

    // prologue: windows for pairs 0..5; P for pairs 0,1 (bumps 0)
    LOADW(0, 0); LOADW(1, 1); LOADW(2, 2);
    LOADW(3, 3); LOADW(4, 4); LOADW(5, 5);
    COMPP(0, 1, 0); COMPP(1, 2, 0);

    // steady: regions r=0..251 in the loop (4 regions / iter), then 252,253
    #pragma unroll 1
    for (int g = 0; g < 63; ++g) {
      const int m8 = 8 * g;
      GROUP2(0, 1, 2, 3, 4, 6, 7, m8 + 6);    // r = 4g
      GROUP2(2, 3, 4, 5, 6, 0, 1, m8 + 8);    // r = 4g+1
      GROUP2(4, 5, 6, 7, 0, 2, 3, m8 + 10);   // r = 4g+2
      GROUP2(6, 7, 0, 1, 2, 4, 5, m8 + 12);   // r = 4g+3
    }
    GROUP2(0, 1, 2, 3, 4, 6, 7, 510);         // r = 252 (chains 504,505)
    GROUP2(2, 3, 4, 5, 6, 0, 1, 512);         // r = 253 (chains 506,507; COMPPs 508,509)
    // tail: COMPP pair 510 (slot 6; X1 = slot 7 = pair 511, loaded r=252),
    // chain pairs 508,509, then 510.
    SB();
    COMPP(6, 7, bq1);
    CHAIN(4, 3); CHAIN(5, 4);
    FEEDBACK();
    SB();
    CHAIN(6, 5);
    Ktot += bq0;   // pair 510's bump, consumed by the tail COMPP

    if (t == 31) {
      // final cell (511,511) = even diag of pair 510, lane31
      // v = -gamma*ln(E_true) = -K1f*(log2(stored) - Ktot)
      unsigned long long bits = __double_as_longlong(dB);
      int ee = (int)((bits >> 52) & 0x7ffull);
      double mant = __longlong_as_double((bits & 0xFFFFFFFFFFFFFull) | (1023ull << 52));
      double l2 = (double)(ee - 1023) + (double)__log2f((float)mant);
      ws[blk] = (float)(-(double)K1f * (l2 - (double)Ktot));
    }
    return;
  }

  // ---------- loss block (blk == 96), 256 threads: 8 per batch element ----------
  const int b = t >> 3, seg = t & 7;

  float s = 0.f;
  {
    const float* mb = mu + b * 64 + seg * 8;
    const float* lb = lv + b * 64 + seg * 8;
    #pragma unroll
    for (int z = 0; z < 8; ++z) {
      float m = mb[z], l = lb[z];
      s += 1.0f + l - m * m - __expf(l);
    }
  }
  s += __shfl_down(s, 4, 8);
  s += __shfl_down(s, 2, 8);
  s += __shfl_down(s, 1, 8);

  float g = 0.f, ps = 0.f;
  {
    const int n0 = seg * 64;
    const int nstart = (seg == 0) ? 1 : n0;
    const float* gb = gt + (size_t)b * SEQ * 4 + 2;
    const float* ab = at + (size_t)b * SEQ * 4 + 2;
    float pg = gb[(nstart - 1) * 4];
    float pp = 1.0f / (1.0f + __expf((0.5f - ab[(nstart - 1) * 4]) * 10.0f));
    for (int n = nstart; n < n0 + 64; ++n) {
      float cg = gb[n * 4]; g += fabsf(cg - pg); pg = cg;
      float cp = 1.0f / (1.0f + __expf((0.5f - ab[n * 4]) * 10.0f));
      ps += fabsf(cp - pp); pp = cp;
    }
  }
  g  += __shfl_down(g, 4, 8);  g  += __shfl_down(g, 2, 8);  g  += __shfl_down(g, 1, 8);
  ps += __shfl_down(ps, 4, 8); ps += __shfl_down(ps, 2, 8); ps += __shfl_down(ps, 1, 8);

  if (seg == 0) {
    s_g[b]  = g;
    s_ps[b] = ps;
    s_kl[b] = fmaxf(-0.5f * s - 0.5f, 0.0f);
  }
  __syncthreads();

  if (t < 32) {
    float gv  = s_g[t];
    float kl  = s_kl[t];
    float d   = ptc[t] - gv;  float aux = d * d;
    float e   = s_ps[t] - gv; float tr  = e * e;
    kl  += __shfl_down(kl, 16, 32); aux += __shfl_down(aux, 16, 32); tr += __shfl_down(tr, 16, 32);
    kl  += __shfl_down(kl,  8, 32); aux += __shfl_down(aux,  8, 32); tr += __shfl_down(tr,  8, 32);
    kl  += __shfl_down(kl,  4, 32); aux += __shfl_down(aux,  4, 32); tr += __shfl_down(tr,  4, 32);
    kl  += __shfl_down(kl,  2, 32); aux += __shfl_down(aux,  2, 32); tr += __shfl_down(tr,  2, 32);
    kl  += __shfl_down(kl,  1, 32); aux += __shfl_down(aux,  1, 32); tr += __shfl_down(tr,  1, 32);
    if (t == 0) { ws[96] = kl; ws[97] = aux; ws[98] = tr; }
  }
}

__global__ __launch_bounds__(64) void sdtw_combine_kernel(
    const float* __restrict__ ws, float* __restrict__ out)
{
  const int t = threadIdx.x;
  float vn = 0.f;
  if (t < 32) vn = ws[t] - 0.5f * (ws[32 + t] + ws[64 + t]);
  vn += __shfl_down(vn, 16, 32);
  vn += __shfl_down(vn,  8, 32);
  vn += __shfl_down(vn,  4, 32);
  vn += __shfl_down(vn,  2, 32);
  vn += __shfl_down(vn,  1, 32);
  if (t == 0) {
    float recon = vn * (1.0f / 1024.0f);   // mean(diag(v)) = sum/1024
    float kl    = ws[96] * (1.0f / 32.0f);
    float aux   = ws[97] * (1.0f / 32.0f);
    float tr    = ws[98] * (1.0f / 32.0f);
    out[0] = recon + kl + 0.1f * aux + 0.5f * tr;
    out[1] = recon;
    out[2] = kl;
    out[3] = aux;
    out[4] = tr;
  }
}

extern "C" void kernel_launch(void* const* d_in, const int* in_sizes, int n_in,
                              void* d_out, int out_size, void* d_ws, size_t ws_size,
                              hipStream_t stream) {
  const float* at  = (const float*)d_in[0];
  const float* mu  = (const float*)d_in[1];
  const float* lv  = (const float*)d_in[2];
  const float* ptc = (const float*)d_in[3];
  const float* gt  = (const float*)d_in[4];
  float* ws  = (float*)d_ws;
  float* out = (float*)d_out;

  sdtw_fused_kernel<<<97, 256, 0, stream>>>(at, mu, lv, ptc, gt, ws);
  sdtw_combine_kernel<<<1, 64, 0, stream>>>(ws, out);
}